// Round 13
// baseline (77.036 us; speedup 1.0000x reference)
//
#include <hip/hip_runtime.h>
#include <math.h>

namespace {
constexpr int S = 64;
constexpr int NP = 131072;
constexpr int H = 32;
constexpr int BLK = 256;
constexpr int NBK = 3 * S;         // 192 buckets: 3*cell + band
constexpr int NBH = 64;            // hist/scatter blocks
constexpr int PPB = NP / NBH;      // 2048 points per hist/scatter block
constexpr int WPB = 4;             // waves per k_main block
constexpr int CHUNK = 64;          // points per wave
constexpr int NCG = 9;             // 9*4*64 = 2304 >= max range (~2160)

typedef float v2f __attribute__((ext_vector_type(2)));
typedef float v4f __attribute__((ext_vector_type(4)));

// LDS slab layout (floats): W_in[64]|b_in[32]|W1[1024]|b1[32]|W2[1024]|b2[32]|Wout[32]|bout
constexpr int LW_WIN  = 0;
constexpr int LW_BIN  = 64;
constexpr int LW_W1   = 96;
constexpr int LW_B1   = 1120;
constexpr int LW_W2   = 1152;
constexpr int LW_B2   = 2176;
constexpr int LW_WOUT = 2208;
constexpr int LW_BOUT = 2240;
constexpr int LW_STR  = 2244;
constexpr int NF4     = 560;       // staged float4 count (2240 floats)

// d_ws layout (ints):
constexpr int WS_OFF  = 0;                    // off[0..192] (193 used, pad 194)
constexpr int WS_BH   = 194;                  // blockhist/bases: NBH*NBK
constexpr int WS_LIST = WS_BH + NBH * NBK;    // NP
constexpr int WS_XS   = WS_LIST + NP;         // float2[NP] (even offset)
constexpr int WS_PART = WS_XS + 2 * NP;       // float2[3][NP] (even offset)

__device__ __forceinline__ float dev_exp2(float v) {
    return __builtin_amdgcn_exp2f(v);
}
__device__ __forceinline__ float fast_tanh(float v) {
    float e = dev_exp2(v * 2.8853900817779268f);     // e^{2v}
    return 1.0f - __fdividef(2.0f, e + 1.0f);
}
__device__ __forceinline__ float fast_sigmoid(float z) {
    return __fdividef(1.0f, 1.0f + dev_exp2(z * -1.4426950408889634f));
}
// bucket key: identical fp ops in k_hist/k_scatter/k_combine (bit-determinism)
__device__ __forceinline__ void cell_band(float xx, int& c, float& frac) {
    float pos = (xx + 1.0f) * 32.0f;
    c = min(S - 1, max(0, (int)floorf(pos)));
    frac = pos - (float)c;
}
__device__ __forceinline__ int band_of(float frac) {
    return (frac > 0.33f ? 1 : 0) + (frac > 0.67f ? 1 : 0);
}

// 64 blocks x 2048 points: per-block LDS histogram, no global atomics
__global__ __launch_bounds__(BLK) void k_hist(const float* __restrict__ x,
                                              int* __restrict__ blockhist) {
    __shared__ int lh[NBK];
    const int tid = threadIdx.x;
    if (tid < NBK) lh[tid] = 0;
    __syncthreads();
    const int pbase = blockIdx.x * PPB;
    for (int t = tid; t < PPB; t += BLK) {
        int c; float frac;
        cell_band(x[2 * (pbase + t) + 1], c, frac);
        atomicAdd(&lh[3 * c + band_of(frac)], 1);    // LDS atomic only
    }
    __syncthreads();
    if (tid < NBK) blockhist[blockIdx.x * NBK + tid] = lh[tid];
}

// 192 threads (3 waves): totals, exclusive scan -> off[0..192], bases in place
__global__ __launch_bounds__(NBK) void k_scan(int* __restrict__ blockhist,
                                              int* __restrict__ off) {
    const int t = threadIdx.x;
    int tot = 0;
    for (int b = 0; b < NBH; ++b) tot += blockhist[b * NBK + t];   // 64 iters
    int incl = tot;
    #pragma unroll
    for (int d = 1; d < 64; d <<= 1) {
        int o = __shfl_up(incl, d);
        if ((t & 63) >= d) incl += o;
    }
    __shared__ int wsum[3];
    if ((t & 63) == 63) wsum[t >> 6] = incl;
    __syncthreads();
    int pre = 0;
    for (int w = 0; w < (t >> 6); ++w) pre += wsum[w];
    const int o = pre + incl - tot;            // exclusive
    off[t] = o;
    if (t == NBK - 1) off[NBK] = pre + incl;   // == NP
    int run = o;
    for (int b = 0; b < NBH; ++b) {
        int v = blockhist[b * NBK + t];
        blockhist[b * NBK + t] = run;
        run += v;
    }
}

// 64 blocks x 2048 points: LDS-rank + per-(block,bucket) base; pre-gather x.
__global__ __launch_bounds__(BLK) void k_scatter(const float* __restrict__ x,
                                                 const int* __restrict__ base,
                                                 int* __restrict__ list,
                                                 float2* __restrict__ xsorted) {
    __shared__ int lh[NBK];
    __shared__ int lbase[NBK];
    const int tid = threadIdx.x;
    if (tid < NBK) { lh[tid] = 0; lbase[tid] = base[blockIdx.x * NBK + tid]; }
    __syncthreads();
    const int pbase = blockIdx.x * PPB;
    for (int t = tid; t < PPB; t += BLK) {
        const int p = pbase + t;
        const float2 xv = ((const float2*)x)[p];
        int c; float frac;
        cell_band(xv.y, c, frac);
        const int k = 3 * c + band_of(frac);
        const int r = atomicAdd(&lh[k], 1);    // LDS atomic only
        const int pos = lbase[k] + r;
        list[pos] = p;
        xsorted[pos] = xv;
    }
}

// grid (S, NCG, 3); block = 256 = 4 waves, one barrier after weight staging.
// Weights staged once per block into LDS (coalesced float4 VMEM), then read as
// broadcast ds_read_b128 -> short pipelined latency instead of s_load round-trips.
// z=0: subnet j own cell; z=1: left-neighbor of cell j+1 (bands A,B);
// z=2: right-neighbor of cell j-1 (bands B,C).
__global__ __launch_bounds__(256, 4) void k_main(
    const float2* __restrict__ xsorted,
    const float* __restrict__ lo_core, const float* __restrict__ hi_core,
    const float* __restrict__ lo_ext,  const float* __restrict__ hi_ext,
    const float* __restrict__ W_in,  const float* __restrict__ b_in,
    const float* __restrict__ W_h1,  const float* __restrict__ b_h1,
    const float* __restrict__ W_h2,  const float* __restrict__ b_h2,
    const float* __restrict__ W_out, const float* __restrict__ b_out,
    const int* __restrict__ off,
    float2* __restrict__ part)
{
    const int j = blockIdx.x;
    const int z = blockIdx.z;
    int lo, hi;
    if (z == 0)      { lo = off[3*j];     hi = off[3*j+3]; }
    else if (z == 1) { if (j + 1 >= S) return; lo = off[3*j+3]; hi = off[3*j+5]; }
    else             { if (j == 0)     return; lo = off[3*j-2]; hi = off[3*j]; }
    const int cnt = hi - lo;
    if (blockIdx.y * (WPB * CHUNK) >= cnt) return;   // whole block idle

    __shared__ __align__(16) float lw[LW_STR];
    {   // cooperative staging: 560 float4 (segments all 16B-aligned per j)
        const int tid = threadIdx.x;
        for (int i = tid; i < NF4; i += BLK) {
            const float4* src;
            if      (i < 16)  src = (const float4*)(W_in  + j * 64)   + i;
            else if (i < 24)  src = (const float4*)(b_in  + j * 32)   + (i - 16);
            else if (i < 280) src = (const float4*)(W_h1  + j * 1024) + (i - 24);
            else if (i < 288) src = (const float4*)(b_h1  + j * 32)   + (i - 280);
            else if (i < 544) src = (const float4*)(W_h2  + j * 1024) + (i - 288);
            else if (i < 552) src = (const float4*)(b_h2  + j * 32)   + (i - 544);
            else              src = (const float4*)(W_out + j * 32)   + (i - 552);
            ((float4*)lw)[i] = *src;
        }
        if (tid == 0) lw[LW_BOUT] = b_out[j];
    }
    __syncthreads();

    const int wid  = threadIdx.x >> 6;
    const int lane = threadIdx.x & 63;
    const int base = (blockIdx.y * WPB + wid) * CHUNK;
    if (base >= cnt) return;                    // wave-uniform exit (no more barriers)
    const int idx = base + lane;
    const bool act = idx < cnt;
    const int slot = lo + (act ? idx : cnt - 1);
    const float2 xv = xsorted[slot];
    const float tt = xv.x, xx = xv.y;

    const float le0 = lo_ext[2*j+0], he0 = hi_ext[2*j+0];
    const float le1 = lo_ext[2*j+1], he1 = hi_ext[2*j+1];
    const float ic0 = (le0 + he0) * 0.5f, ih0 = __fdividef(1.0f, (he0 - le0) * 0.5f);
    const float ic1 = (le1 + he1) * 0.5f, ih1 = __fdividef(1.0f, (he1 - le1) * 0.5f);
    const v2f xn = {(tt - ic0) * ih0, (xx - ic1) * ih1};

    v2f h0[H/2], h1[H/2];                       // activations as packed pairs
    {   // input layer (v2f weight pairs from LDS)
        const v2f* Wiv = (const v2f*)(lw + LW_WIN);
        const float* bi = lw + LW_BIN;
        #pragma unroll
        for (int k2 = 0; k2 < H/2; ++k2) {
            v2f aA = __builtin_elementwise_fma(xn, Wiv[2*k2+0], (v2f){bi[2*k2+0], 0.0f});
            v2f aB = __builtin_elementwise_fma(xn, Wiv[2*k2+1], (v2f){bi[2*k2+1], 0.0f});
            h0[k2] = (v2f){fast_tanh(aA.x + aA.y), fast_tanh(aB.x + aB.y)};
        }
    }
    {   // hidden 1: rows as v4f (ds_read_b128 broadcast), unpack to v2f pairs
        const v4f* W1v = (const v4f*)(lw + LW_W1);
        const float* b1 = lw + LW_B1;
        #pragma unroll
        for (int k2 = 0; k2 < H/2; ++k2) {
            const v4f* rowA = W1v + (2*k2) * (H/4);
            const v4f* rowB = rowA + (H/4);
            v2f aA = {b1[2*k2+0], 0.0f};
            v2f aB = {b1[2*k2+1], 0.0f};
            #pragma unroll
            for (int q4 = 0; q4 < H/4; ++q4) {
                const v4f wA = rowA[q4];
                const v4f wB = rowB[q4];
                aA = __builtin_elementwise_fma(h0[2*q4+0], (v2f){wA.x, wA.y}, aA);
                aA = __builtin_elementwise_fma(h0[2*q4+1], (v2f){wA.z, wA.w}, aA);
                aB = __builtin_elementwise_fma(h0[2*q4+0], (v2f){wB.x, wB.y}, aB);
                aB = __builtin_elementwise_fma(h0[2*q4+1], (v2f){wB.z, wB.w}, aB);
            }
            h1[k2] = (v2f){fast_tanh(aA.x + aA.y), fast_tanh(aB.x + aB.y)};
        }
    }
    {   // hidden 2
        const v4f* W2v = (const v4f*)(lw + LW_W2);
        const float* b2 = lw + LW_B2;
        #pragma unroll
        for (int k2 = 0; k2 < H/2; ++k2) {
            const v4f* rowA = W2v + (2*k2) * (H/4);
            const v4f* rowB = rowA + (H/4);
            v2f aA = {b2[2*k2+0], 0.0f};
            v2f aB = {b2[2*k2+1], 0.0f};
            #pragma unroll
            for (int q4 = 0; q4 < H/4; ++q4) {
                const v4f wA = rowA[q4];
                const v4f wB = rowB[q4];
                aA = __builtin_elementwise_fma(h1[2*q4+0], (v2f){wA.x, wA.y}, aA);
                aA = __builtin_elementwise_fma(h1[2*q4+1], (v2f){wA.z, wA.w}, aA);
                aB = __builtin_elementwise_fma(h1[2*q4+0], (v2f){wB.x, wB.y}, aB);
                aB = __builtin_elementwise_fma(h1[2*q4+1], (v2f){wB.z, wB.w}, aB);
            }
            h0[k2] = (v2f){fast_tanh(aA.x + aA.y), fast_tanh(aB.x + aB.y)};   // reuse
        }
    }
    float acc;
    {   // output layer
        const v4f* Wov = (const v4f*)(lw + LW_WOUT);
        v2f a = {lw[LW_BOUT], 0.0f};
        #pragma unroll
        for (int q4 = 0; q4 < H/4; ++q4) {
            const v4f w = Wov[q4];
            a = __builtin_elementwise_fma(h0[2*q4+0], (v2f){w.x, w.y}, a);
            a = __builtin_elementwise_fma(h0[2*q4+1], (v2f){w.z, w.w}, a);
        }
        acc = a.x + a.y;
    }

    float w = 1.0f;
    {
        const float lc = lo_core[2*j+0], hc = hi_core[2*j+0];
        const float ov = fmaxf(he0 - hc, lc - le0);
        const float sc = __fdividef(4.0f, fmaf(2.0f * ov, he0 - le0, 1e-8f));
        w *= fast_sigmoid(sc * (tt - lc)) * fast_sigmoid(sc * (hc - tt));
    }
    {
        const float lc = lo_core[2*j+1], hc = hi_core[2*j+1];
        const float ov = fmaxf(he1 - hc, lc - le1);
        const float sc = __fdividef(4.0f, fmaf(2.0f * ov, he1 - le1, 1e-8f));
        w *= fast_sigmoid(sc * (xx - lc)) * fast_sigmoid(sc * (hc - xx));
    }
    if (act) part[z * NP + slot] = make_float2(acc * w, w);
}

// combine (left, own, right in reference j-order) + hard-BC epilogue
__global__ __launch_bounds__(BLK) void k_combine(
    const float2* __restrict__ part,
    const float2* __restrict__ xsorted,
    const int* __restrict__ list,
    float* __restrict__ out)
{
    const int i = blockIdx.x * BLK + threadIdx.x;
    const float2 xv = xsorted[i];
    const float tt = xv.x, xx = xv.y;
    int c; float frac;
    cell_band(xx, c, frac);
    float nsum = 0.0f, dsum = 0.0f;
    if (c > 0 && !(frac > 0.67f)) {            // left subnet written by z=1 of j=c-1
        const float2 p1 = part[NP + i];
        nsum = p1.x; dsum = p1.y;
    }
    const float2 p0 = part[i];                 // own subnet (z=0)
    nsum += p0.x; dsum += p0.y;
    if (c < S - 1 && frac > 0.33f) {           // right subnet written by z=2 of j=c+1
        const float2 p2 = part[2 * NP + i];
        nsum += p2.x; dsum += p2.y;
    }
    const float u = __fdividef(nsum, dsum + 1e-8f);
    const float g = -sinf(3.14159265358979323846f * xx);
    const float factor = fast_tanh(xx + 1.0f) * fast_tanh(xx - 1.0f) * fast_tanh(tt);
    out[list[i]] = fmaf(factor, u, g);
}
} // namespace

extern "C" void kernel_launch(void* const* d_in, const int* in_sizes, int n_in,
                              void* d_out, int out_size, void* d_ws, size_t ws_size,
                              hipStream_t stream) {
    const float* x       = (const float*)d_in[0];
    const float* lo_core = (const float*)d_in[1];
    const float* hi_core = (const float*)d_in[2];
    const float* lo_ext  = (const float*)d_in[3];
    const float* hi_ext  = (const float*)d_in[4];
    const float* W_in    = (const float*)d_in[5];
    const float* b_in    = (const float*)d_in[6];
    const float* W_h1    = (const float*)d_in[7];
    const float* b_h1    = (const float*)d_in[8];
    const float* W_h2    = (const float*)d_in[9];
    const float* b_h2    = (const float*)d_in[10];
    const float* W_out   = (const float*)d_in[11];
    const float* b_out   = (const float*)d_in[12];
    float* out = (float*)d_out;

    int* ws        = (int*)d_ws;
    int* off       = ws + WS_OFF;
    int* blockhist = ws + WS_BH;      // becomes per-(block,bucket) base after k_scan
    int* list      = ws + WS_LIST;
    float2* xsorted = (float2*)(ws + WS_XS);
    float2* part    = (float2*)(ws + WS_PART);

    hipLaunchKernelGGL(k_hist,    dim3(NBH),       dim3(BLK), 0, stream, x, blockhist);
    hipLaunchKernelGGL(k_scan,    dim3(1),         dim3(NBK), 0, stream, blockhist, off);
    hipLaunchKernelGGL(k_scatter, dim3(NBH),       dim3(BLK), 0, stream, x, blockhist, list, xsorted);
    hipLaunchKernelGGL(k_main,    dim3(S, NCG, 3), dim3(256), 0, stream,
        xsorted, lo_core, hi_core, lo_ext, hi_ext, W_in, b_in, W_h1, b_h1,
        W_h2, b_h2, W_out, b_out, off, part);
    hipLaunchKernelGGL(k_combine, dim3(NP / BLK),  dim3(BLK), 0, stream, part, xsorted, list, out);
}

// Round 14
// 59.018 us; speedup vs baseline: 1.3053x; 1.3053x over previous
//
#include <hip/hip_runtime.h>
#include <math.h>

namespace {
constexpr int S = 64;
constexpr int NP = 131072;
constexpr int H = 32;
constexpr int BLK = 256;
constexpr int NBK = 3 * S;         // 192 buckets: 3*cell + band
constexpr int NBH = 64;            // hist/scatter blocks
constexpr int PPB = NP / NBH;      // 2048 points per hist/scatter block
constexpr int WPB = 4;             // waves per k_main block
constexpr int CHUNK = 64;          // points per wave
constexpr int NCG = 9;             // 9*4*64 = 2304 >= max range (~2160)

typedef float v2f __attribute__((ext_vector_type(2)));

// d_ws layout (ints):
constexpr int WS_OFF  = 0;                    // off[0..192] (193 used, pad 194)
constexpr int WS_BH   = 194;                  // blockhist/bases: NBH*NBK
constexpr int WS_LIST = WS_BH + NBH * NBK;    // NP
constexpr int WS_XS   = WS_LIST + NP;         // float2[NP] (even offset)
constexpr int WS_PART = WS_XS + 2 * NP;       // float2[3][NP] (even offset)

__device__ __forceinline__ float dev_exp2(float v) {
    return __builtin_amdgcn_exp2f(v);
}
__device__ __forceinline__ float fast_tanh(float v) {
    float e = dev_exp2(v * 2.8853900817779268f);     // e^{2v}
    return 1.0f - __fdividef(2.0f, e + 1.0f);
}
__device__ __forceinline__ float fast_sigmoid(float z) {
    return __fdividef(1.0f, 1.0f + dev_exp2(z * -1.4426950408889634f));
}
// bucket key: identical fp ops in k_hist/k_scatter/k_combine (bit-determinism)
__device__ __forceinline__ void cell_band(float xx, int& c, float& frac) {
    float pos = (xx + 1.0f) * 32.0f;
    c = min(S - 1, max(0, (int)floorf(pos)));
    frac = pos - (float)c;
}
__device__ __forceinline__ int band_of(float frac) {
    return (frac > 0.33f ? 1 : 0) + (frac > 0.67f ? 1 : 0);
}

// 64 blocks x 2048 points: per-block LDS histogram, no global atomics
__global__ __launch_bounds__(BLK) void k_hist(const float* __restrict__ x,
                                              int* __restrict__ blockhist) {
    __shared__ int lh[NBK];
    const int tid = threadIdx.x;
    if (tid < NBK) lh[tid] = 0;
    __syncthreads();
    const int pbase = blockIdx.x * PPB;
    for (int t = tid; t < PPB; t += BLK) {
        int c; float frac;
        cell_band(x[2 * (pbase + t) + 1], c, frac);
        atomicAdd(&lh[3 * c + band_of(frac)], 1);    // LDS atomic only
    }
    __syncthreads();
    if (tid < NBK) blockhist[blockIdx.x * NBK + tid] = lh[tid];
}

// 192 threads (3 waves): totals, exclusive scan -> off[0..192], bases in place
__global__ __launch_bounds__(NBK) void k_scan(int* __restrict__ blockhist,
                                              int* __restrict__ off) {
    const int t = threadIdx.x;
    int tot = 0;
    for (int b = 0; b < NBH; ++b) tot += blockhist[b * NBK + t];   // 64 iters
    int incl = tot;
    #pragma unroll
    for (int d = 1; d < 64; d <<= 1) {
        int o = __shfl_up(incl, d);
        if ((t & 63) >= d) incl += o;
    }
    __shared__ int wsum[3];
    if ((t & 63) == 63) wsum[t >> 6] = incl;
    __syncthreads();
    int pre = 0;
    for (int w = 0; w < (t >> 6); ++w) pre += wsum[w];
    const int o = pre + incl - tot;            // exclusive
    off[t] = o;
    if (t == NBK - 1) off[NBK] = pre + incl;   // == NP
    int run = o;
    for (int b = 0; b < NBH; ++b) {
        int v = blockhist[b * NBK + t];
        blockhist[b * NBK + t] = run;
        run += v;
    }
}

// 64 blocks x 2048 points: LDS-rank + per-(block,bucket) base; pre-gather x.
// Intra-bucket order nondeterministic; per-point values are order-independent.
__global__ __launch_bounds__(BLK) void k_scatter(const float* __restrict__ x,
                                                 const int* __restrict__ base,
                                                 int* __restrict__ list,
                                                 float2* __restrict__ xsorted) {
    __shared__ int lh[NBK];
    __shared__ int lbase[NBK];
    const int tid = threadIdx.x;
    if (tid < NBK) { lh[tid] = 0; lbase[tid] = base[blockIdx.x * NBK + tid]; }
    __syncthreads();
    const int pbase = blockIdx.x * PPB;
    for (int t = tid; t < PPB; t += BLK) {
        const int p = pbase + t;
        const float2 xv = ((const float2*)x)[p];
        int c; float frac;
        cell_band(xv.y, c, frac);
        const int k = 3 * c + band_of(frac);
        const int r = atomicAdd(&lh[k], 1);    // LDS atomic only
        const int pos = lbase[k] + r;
        list[pos] = p;
        xsorted[pos] = xv;
    }
}

// ROUND-10 BODY (measured best: 44 us). grid (S, NCG, 3); block = 256 = 4
// independent waves, no barriers/LDS; s_load weight stream + packed-v2f math.
// z=0: subnet j own cell; z=1: left-neighbor of cell j+1 (bands A,B);
// z=2: right-neighbor of cell j-1 (bands B,C).
__global__ __launch_bounds__(256, 3) void k_main(
    const float2* __restrict__ xsorted,
    const float* __restrict__ lo_core, const float* __restrict__ hi_core,
    const float* __restrict__ lo_ext,  const float* __restrict__ hi_ext,
    const float* __restrict__ W_in,  const float* __restrict__ b_in,
    const float* __restrict__ W_h1,  const float* __restrict__ b_h1,
    const float* __restrict__ W_h2,  const float* __restrict__ b_h2,
    const float* __restrict__ W_out, const float* __restrict__ b_out,
    const int* __restrict__ off,
    float2* __restrict__ part)
{
    const int j = blockIdx.x;
    const int z = blockIdx.z;
    int lo, hi;
    if (z == 0)      { lo = off[3*j];     hi = off[3*j+3]; }
    else if (z == 1) { if (j + 1 >= S) return; lo = off[3*j+3]; hi = off[3*j+5]; }
    else             { if (j == 0)     return; lo = off[3*j-2]; hi = off[3*j]; }
    const int cnt = hi - lo;
    const int wid  = threadIdx.x >> 6;
    const int lane = threadIdx.x & 63;
    const int base = (blockIdx.y * WPB + wid) * CHUNK;
    if (base >= cnt) return;                    // wave-uniform exit
    const int idx = base + lane;
    const bool act = idx < cnt;
    const int slot = lo + (act ? idx : cnt - 1);
    const float2 xv = xsorted[slot];
    const float tt = xv.x, xx = xv.y;

    const float le0 = lo_ext[2*j+0], he0 = hi_ext[2*j+0];
    const float le1 = lo_ext[2*j+1], he1 = hi_ext[2*j+1];
    const float ic0 = (le0 + he0) * 0.5f, ih0 = __fdividef(1.0f, (he0 - le0) * 0.5f);
    const float ic1 = (le1 + he1) * 0.5f, ih1 = __fdividef(1.0f, (he1 - le1) * 0.5f);
    const float xn0 = (tt - ic0) * ih0;
    const float xn1 = (xx - ic1) * ih1;
    const v2f xn = {xn0, xn1};

    v2f h0[H/2], h1[H/2];                       // activations as packed pairs

    {   // input layer: neuron k weight pair = {W[2k],W[2k+1]}
        const v2f* Wiv = (const v2f*)(W_in + j * (H * 2));
        const float* bi = b_in + j * H;
        #pragma unroll
        for (int k2 = 0; k2 < H/2; ++k2) {
            v2f aA = __builtin_elementwise_fma(xn, Wiv[2*k2+0], (v2f){bi[2*k2+0], 0.0f});
            v2f aB = __builtin_elementwise_fma(xn, Wiv[2*k2+1], (v2f){bi[2*k2+1], 0.0f});
            h0[k2] = (v2f){fast_tanh(aA.x + aA.y), fast_tanh(aB.x + aB.y)};
        }
    }
    {   // hidden layer 1: neurons in pairs, two independent packed chains
        const v2f* W1v = (const v2f*)(W_h1 + j * (H * H));
        const float* b1 = b_h1 + j * H;
        #pragma unroll
        for (int k2 = 0; k2 < H/2; ++k2) {
            const v2f* rowA = W1v + (2*k2) * (H/2);
            const v2f* rowB = rowA + (H/2);
            v2f aA = {b1[2*k2+0], 0.0f};
            v2f aB = {b1[2*k2+1], 0.0f};
            #pragma unroll
            for (int q2 = 0; q2 < H/2; ++q2) {
                aA = __builtin_elementwise_fma(h0[q2], rowA[q2], aA);
                aB = __builtin_elementwise_fma(h0[q2], rowB[q2], aB);
            }
            h1[k2] = (v2f){fast_tanh(aA.x + aA.y), fast_tanh(aB.x + aB.y)};
        }
    }
    {   // hidden layer 2
        const v2f* W2v = (const v2f*)(W_h2 + j * (H * H));
        const float* b2 = b_h2 + j * H;
        #pragma unroll
        for (int k2 = 0; k2 < H/2; ++k2) {
            const v2f* rowA = W2v + (2*k2) * (H/2);
            const v2f* rowB = rowA + (H/2);
            v2f aA = {b2[2*k2+0], 0.0f};
            v2f aB = {b2[2*k2+1], 0.0f};
            #pragma unroll
            for (int q2 = 0; q2 < H/2; ++q2) {
                aA = __builtin_elementwise_fma(h1[q2], rowA[q2], aA);
                aB = __builtin_elementwise_fma(h1[q2], rowB[q2], aB);
            }
            h0[k2] = (v2f){fast_tanh(aA.x + aA.y), fast_tanh(aB.x + aB.y)};   // reuse
        }
    }
    float acc;
    {   // output layer
        const v2f* Wov = (const v2f*)(W_out + j * H);
        v2f a = {b_out[j], 0.0f};
        #pragma unroll
        for (int q2 = 0; q2 < H/2; ++q2) {
            a = __builtin_elementwise_fma(h0[q2], Wov[q2], a);
        }
        acc = a.x + a.y;
    }

    float w = 1.0f;
    {
        const float lc = lo_core[2*j+0], hc = hi_core[2*j+0];
        const float ov = fmaxf(he0 - hc, lc - le0);
        const float sc = __fdividef(4.0f, fmaf(2.0f * ov, he0 - le0, 1e-8f));
        w *= fast_sigmoid(sc * (tt - lc)) * fast_sigmoid(sc * (hc - tt));
    }
    {
        const float lc = lo_core[2*j+1], hc = hi_core[2*j+1];
        const float ov = fmaxf(he1 - hc, lc - le1);
        const float sc = __fdividef(4.0f, fmaf(2.0f * ov, he1 - le1, 1e-8f));
        w *= fast_sigmoid(sc * (xx - lc)) * fast_sigmoid(sc * (hc - xx));
    }
    if (act) part[z * NP + slot] = make_float2(acc * w, w);
}

// combine (left, own, right in reference j-order) + hard-BC epilogue
__global__ __launch_bounds__(BLK) void k_combine(
    const float2* __restrict__ part,
    const float2* __restrict__ xsorted,
    const int* __restrict__ list,
    float* __restrict__ out)
{
    const int i = blockIdx.x * BLK + threadIdx.x;
    const float2 xv = xsorted[i];
    const float tt = xv.x, xx = xv.y;
    int c; float frac;
    cell_band(xx, c, frac);
    float nsum = 0.0f, dsum = 0.0f;
    if (c > 0 && !(frac > 0.67f)) {            // left subnet written by z=1 of j=c-1
        const float2 p1 = part[NP + i];
        nsum = p1.x; dsum = p1.y;
    }
    const float2 p0 = part[i];                 // own subnet (z=0)
    nsum += p0.x; dsum += p0.y;
    if (c < S - 1 && frac > 0.33f) {           // right subnet written by z=2 of j=c+1
        const float2 p2 = part[2 * NP + i];
        nsum += p2.x; dsum += p2.y;
    }
    const float u = __fdividef(nsum, dsum + 1e-8f);
    const float g = -sinf(3.14159265358979323846f * xx);
    const float factor = fast_tanh(xx + 1.0f) * fast_tanh(xx - 1.0f) * fast_tanh(tt);
    out[list[i]] = fmaf(factor, u, g);
}
} // namespace

extern "C" void kernel_launch(void* const* d_in, const int* in_sizes, int n_in,
                              void* d_out, int out_size, void* d_ws, size_t ws_size,
                              hipStream_t stream) {
    const float* x       = (const float*)d_in[0];
    const float* lo_core = (const float*)d_in[1];
    const float* hi_core = (const float*)d_in[2];
    const float* lo_ext  = (const float*)d_in[3];
    const float* hi_ext  = (const float*)d_in[4];
    const float* W_in    = (const float*)d_in[5];
    const float* b_in    = (const float*)d_in[6];
    const float* W_h1    = (const float*)d_in[7];
    const float* b_h1    = (const float*)d_in[8];
    const float* W_h2    = (const float*)d_in[9];
    const float* b_h2    = (const float*)d_in[10];
    const float* W_out   = (const float*)d_in[11];
    const float* b_out   = (const float*)d_in[12];
    float* out = (float*)d_out;

    int* ws        = (int*)d_ws;
    int* off       = ws + WS_OFF;
    int* blockhist = ws + WS_BH;      // becomes per-(block,bucket) base after k_scan
    int* list      = ws + WS_LIST;
    float2* xsorted = (float2*)(ws + WS_XS);
    float2* part    = (float2*)(ws + WS_PART);

    hipLaunchKernelGGL(k_hist,    dim3(NBH),       dim3(BLK), 0, stream, x, blockhist);
    hipLaunchKernelGGL(k_scan,    dim3(1),         dim3(NBK), 0, stream, blockhist, off);
    hipLaunchKernelGGL(k_scatter, dim3(NBH),       dim3(BLK), 0, stream, x, blockhist, list, xsorted);
    hipLaunchKernelGGL(k_main,    dim3(S, NCG, 3), dim3(256), 0, stream,
        xsorted, lo_core, hi_core, lo_ext, hi_ext, W_in, b_in, W_h1, b_h1,
        W_h2, b_h2, W_out, b_out, off, part);
    hipLaunchKernelGGL(k_combine, dim3(NP / BLK),  dim3(BLK), 0, stream, part, xsorted, list, out);
}

// Round 15
// 57.376 us; speedup vs baseline: 1.3426x; 1.0286x over previous
//
#include <hip/hip_runtime.h>
#include <math.h>

namespace {
constexpr int S = 64;
constexpr int NP = 131072;
constexpr int H = 32;
constexpr int BLK = 256;
constexpr int NBK = 3 * S;         // 192 buckets: 3*cell + band
constexpr int NBH = 64;            // hist/scatter blocks
constexpr int PPB = NP / NBH;      // 2048 points per hist/scatter block
constexpr int WPB = 4;             // waves per k_main block
constexpr int NCH_MAX = 6400;      // >= absolute worst-case chunk count (6336)
constexpr int NMB = NCH_MAX / WPB; // 1600 k_main blocks

typedef float v2f __attribute__((ext_vector_type(2)));

// d_ws layout (ints):
constexpr int WS_OFF  = 0;                    // off[0..192]
constexpr int WS_NCH  = 193;                  // worklist length (1 int)
constexpr int WS_BH   = 194;                  // blockhist/bases: NBH*NBK
constexpr int WS_LIST = WS_BH + NBH * NBK;    // NP
constexpr int WS_XS   = WS_LIST + NP;         // float2[NP] (even offset)
constexpr int WS_PART = WS_XS + 2 * NP;       // float2[3][NP] (even offset)
constexpr int WS_DESC = WS_PART + 6 * NP;     // int2[NCH_MAX]

__device__ __forceinline__ float dev_exp2(float v) {
    return __builtin_amdgcn_exp2f(v);
}
__device__ __forceinline__ float fast_tanh(float v) {
    float e = dev_exp2(v * 2.8853900817779268f);     // e^{2v}
    return 1.0f - __fdividef(2.0f, e + 1.0f);
}
__device__ __forceinline__ float fast_sigmoid(float z) {
    return __fdividef(1.0f, 1.0f + dev_exp2(z * -1.4426950408889634f));
}
// bucket key: identical fp ops in k_hist/k_scatter/k_combine (bit-determinism)
__device__ __forceinline__ void cell_band(float xx, int& c, float& frac) {
    float pos = (xx + 1.0f) * 32.0f;
    c = min(S - 1, max(0, (int)floorf(pos)));
    frac = pos - (float)c;
}
__device__ __forceinline__ int band_of(float frac) {
    return (frac > 0.33f ? 1 : 0) + (frac > 0.67f ? 1 : 0);
}

// 64 blocks x 2048 points: per-block LDS histogram, no global atomics
__global__ __launch_bounds__(BLK) void k_hist(const float* __restrict__ x,
                                              int* __restrict__ blockhist) {
    __shared__ int lh[NBK];
    const int tid = threadIdx.x;
    if (tid < NBK) lh[tid] = 0;
    __syncthreads();
    const int pbase = blockIdx.x * PPB;
    for (int t = tid; t < PPB; t += BLK) {
        int c; float frac;
        cell_band(x[2 * (pbase + t) + 1], c, frac);
        atomicAdd(&lh[3 * c + band_of(frac)], 1);    // LDS atomic only
    }
    __syncthreads();
    if (tid < NBK) blockhist[blockIdx.x * NBK + tid] = lh[tid];
}

// 192 threads (3 waves): bucket scan -> off[], per-(block,bucket) bases,
// then build the exact per-chunk worklist (descriptor = {slot_base, len|j|z}).
__global__ __launch_bounds__(NBK) void k_scan(int* __restrict__ blockhist,
                                              int* __restrict__ off,
                                              int* __restrict__ nch,
                                              int2* __restrict__ desc) {
    __shared__ int loff[NBK + 1];
    __shared__ int wsum[3];
    __shared__ int wsum2[3];
    const int t = threadIdx.x;
    int tot = 0;
    for (int b = 0; b < NBH; ++b) tot += blockhist[b * NBK + t];   // 64 iters
    int incl = tot;
    #pragma unroll
    for (int d = 1; d < 64; d <<= 1) {
        int o = __shfl_up(incl, d);
        if ((t & 63) >= d) incl += o;
    }
    if ((t & 63) == 63) wsum[t >> 6] = incl;
    __syncthreads();
    int pre = 0;
    for (int w = 0; w < (t >> 6); ++w) pre += wsum[w];
    const int o = pre + incl - tot;            // exclusive
    off[t] = o;  loff[t] = o;
    if (t == NBK - 1) { off[NBK] = pre + incl; loff[NBK] = pre + incl; }
    int run = o;
    for (int b = 0; b < NBH; ++b) {
        int v = blockhist[b * NBK + t];
        blockhist[b * NBK + t] = run;
        run += v;
    }
    __syncthreads();

    // ---- worklist: thread t = range (j = t/3, z = t%3) ----
    const int j = t / 3;
    const int z = t - 3 * j;
    int lo2 = 0, hi2 = 0;
    if (z == 0)                { lo2 = loff[3*j];   hi2 = loff[3*j+3]; }
    else if (z == 1 && j+1 < S){ lo2 = loff[3*j+3]; hi2 = loff[3*j+5]; }
    else if (z == 2 && j > 0)  { lo2 = loff[3*j-2]; hi2 = loff[3*j]; }
    const int cnt = hi2 - lo2;
    const int cc  = (cnt + 63) >> 6;           // chunks for this range
    int incl2 = cc;
    #pragma unroll
    for (int d = 1; d < 64; d <<= 1) {
        int o2 = __shfl_up(incl2, d);
        if ((t & 63) >= d) incl2 += o2;
    }
    if ((t & 63) == 63) wsum2[t >> 6] = incl2;
    __syncthreads();
    int pre2 = 0;
    for (int w = 0; w < (t >> 6); ++w) pre2 += wsum2[w];
    const int pos = pre2 + incl2 - cc;         // exclusive
    if (t == NBK - 1) nch[0] = pre2 + incl2;
    for (int i = 0; i < cc; ++i) {
        const int rem = cnt - (i << 6);
        const int len = rem < 64 ? rem : 64;
        desc[pos + i] = make_int2(lo2 + (i << 6), len | (j << 8) | (z << 16));
    }
}

// 64 blocks x 2048 points: LDS-rank + per-(block,bucket) base; pre-gather x.
// Intra-bucket order nondeterministic; per-point values are order-independent.
__global__ __launch_bounds__(BLK) void k_scatter(const float* __restrict__ x,
                                                 const int* __restrict__ base,
                                                 int* __restrict__ list,
                                                 float2* __restrict__ xsorted) {
    __shared__ int lh[NBK];
    __shared__ int lbase[NBK];
    const int tid = threadIdx.x;
    if (tid < NBK) { lh[tid] = 0; lbase[tid] = base[blockIdx.x * NBK + tid]; }
    __syncthreads();
    const int pbase = blockIdx.x * PPB;
    for (int t = tid; t < PPB; t += BLK) {
        const int p = pbase + t;
        const float2 xv = ((const float2*)x)[p];
        int c; float frac;
        cell_band(xv.y, c, frac);
        const int k = 3 * c + band_of(frac);
        const int r = atomicAdd(&lh[k], 1);    // LDS atomic only
        const int pos = lbase[k] + r;
        list[pos] = p;
        xsorted[pos] = xv;
    }
}

// Flat 1D grid over the exact chunk worklist; 4 independent waves per block.
// Wave w: desc[w] = {slot_base, len|j<<8|z<<16}; j via readfirstlane -> SGPR ->
// all weight addressing scalar (s_load), body = proven round-10 packed-v2f.
__global__ __launch_bounds__(256, 4) void k_main(
    const float2* __restrict__ xsorted,
    const float* __restrict__ lo_core, const float* __restrict__ hi_core,
    const float* __restrict__ lo_ext,  const float* __restrict__ hi_ext,
    const float* __restrict__ W_in,  const float* __restrict__ b_in,
    const float* __restrict__ W_h1,  const float* __restrict__ b_h1,
    const float* __restrict__ W_h2,  const float* __restrict__ b_h2,
    const float* __restrict__ W_out, const float* __restrict__ b_out,
    const int* __restrict__ nch, const int2* __restrict__ desc,
    float2* __restrict__ part)
{
    const int wid  = threadIdx.x >> 6;
    const int lane = threadIdx.x & 63;
    const int w = blockIdx.x * WPB + wid;
    if (w >= nch[0]) return;                   // wave-uniform exit
    const int2 d = desc[w];
    const int slot0 = __builtin_amdgcn_readfirstlane(d.x);
    const int meta  = __builtin_amdgcn_readfirstlane(d.y);
    const int len = meta & 255;
    const int j   = (meta >> 8) & 255;         // SGPR -> scalar weight addressing
    const int z   = meta >> 16;
    const bool act = lane < len;
    const int slot = slot0 + (act ? lane : len - 1);
    const float2 xv = xsorted[slot];
    const float tt = xv.x, xx = xv.y;

    const float le0 = lo_ext[2*j+0], he0 = hi_ext[2*j+0];
    const float le1 = lo_ext[2*j+1], he1 = hi_ext[2*j+1];
    const float ic0 = (le0 + he0) * 0.5f, ih0 = __fdividef(1.0f, (he0 - le0) * 0.5f);
    const float ic1 = (le1 + he1) * 0.5f, ih1 = __fdividef(1.0f, (he1 - le1) * 0.5f);
    const v2f xn = {(tt - ic0) * ih0, (xx - ic1) * ih1};

    v2f h0[H/2], h1[H/2];                       // activations as packed pairs

    {   // input layer: neuron k weight pair = {W[2k],W[2k+1]}
        const v2f* Wiv = (const v2f*)(W_in + j * (H * 2));
        const float* bi = b_in + j * H;
        #pragma unroll
        for (int k2 = 0; k2 < H/2; ++k2) {
            v2f aA = __builtin_elementwise_fma(xn, Wiv[2*k2+0], (v2f){bi[2*k2+0], 0.0f});
            v2f aB = __builtin_elementwise_fma(xn, Wiv[2*k2+1], (v2f){bi[2*k2+1], 0.0f});
            h0[k2] = (v2f){fast_tanh(aA.x + aA.y), fast_tanh(aB.x + aB.y)};
        }
    }
    {   // hidden layer 1: neurons in pairs, two independent packed chains
        const v2f* W1v = (const v2f*)(W_h1 + j * (H * H));
        const float* b1 = b_h1 + j * H;
        #pragma unroll
        for (int k2 = 0; k2 < H/2; ++k2) {
            const v2f* rowA = W1v + (2*k2) * (H/2);
            const v2f* rowB = rowA + (H/2);
            v2f aA = {b1[2*k2+0], 0.0f};
            v2f aB = {b1[2*k2+1], 0.0f};
            #pragma unroll
            for (int q2 = 0; q2 < H/2; ++q2) {
                aA = __builtin_elementwise_fma(h0[q2], rowA[q2], aA);
                aB = __builtin_elementwise_fma(h0[q2], rowB[q2], aB);
            }
            h1[k2] = (v2f){fast_tanh(aA.x + aA.y), fast_tanh(aB.x + aB.y)};
        }
    }
    {   // hidden layer 2
        const v2f* W2v = (const v2f*)(W_h2 + j * (H * H));
        const float* b2 = b_h2 + j * H;
        #pragma unroll
        for (int k2 = 0; k2 < H/2; ++k2) {
            const v2f* rowA = W2v + (2*k2) * (H/2);
            const v2f* rowB = rowA + (H/2);
            v2f aA = {b2[2*k2+0], 0.0f};
            v2f aB = {b2[2*k2+1], 0.0f};
            #pragma unroll
            for (int q2 = 0; q2 < H/2; ++q2) {
                aA = __builtin_elementwise_fma(h1[q2], rowA[q2], aA);
                aB = __builtin_elementwise_fma(h1[q2], rowB[q2], aB);
            }
            h0[k2] = (v2f){fast_tanh(aA.x + aA.y), fast_tanh(aB.x + aB.y)};   // reuse
        }
    }
    float acc;
    {   // output layer
        const v2f* Wov = (const v2f*)(W_out + j * H);
        v2f a = {b_out[j], 0.0f};
        #pragma unroll
        for (int q2 = 0; q2 < H/2; ++q2) {
            a = __builtin_elementwise_fma(h0[q2], Wov[q2], a);
        }
        acc = a.x + a.y;
    }

    float w2 = 1.0f;
    {
        const float lc = lo_core[2*j+0], hc = hi_core[2*j+0];
        const float ov = fmaxf(he0 - hc, lc - le0);
        const float sc = __fdividef(4.0f, fmaf(2.0f * ov, he0 - le0, 1e-8f));
        w2 *= fast_sigmoid(sc * (tt - lc)) * fast_sigmoid(sc * (hc - tt));
    }
    {
        const float lc = lo_core[2*j+1], hc = hi_core[2*j+1];
        const float ov = fmaxf(he1 - hc, lc - le1);
        const float sc = __fdividef(4.0f, fmaf(2.0f * ov, he1 - le1, 1e-8f));
        w2 *= fast_sigmoid(sc * (xx - lc)) * fast_sigmoid(sc * (hc - xx));
    }
    if (act) part[z * NP + slot] = make_float2(acc * w2, w2);
}

// combine (left, own, right in reference j-order) + hard-BC epilogue
__global__ __launch_bounds__(BLK) void k_combine(
    const float2* __restrict__ part,
    const float2* __restrict__ xsorted,
    const int* __restrict__ list,
    float* __restrict__ out)
{
    const int i = blockIdx.x * BLK + threadIdx.x;
    const float2 xv = xsorted[i];
    const float tt = xv.x, xx = xv.y;
    int c; float frac;
    cell_band(xx, c, frac);
    float nsum = 0.0f, dsum = 0.0f;
    if (c > 0 && !(frac > 0.67f)) {            // left subnet written by z=1 of j=c-1
        const float2 p1 = part[NP + i];
        nsum = p1.x; dsum = p1.y;
    }
    const float2 p0 = part[i];                 // own subnet (z=0)
    nsum += p0.x; dsum += p0.y;
    if (c < S - 1 && frac > 0.33f) {           // right subnet written by z=2 of j=c+1
        const float2 p2 = part[2 * NP + i];
        nsum += p2.x; dsum += p2.y;
    }
    const float u = __fdividef(nsum, dsum + 1e-8f);
    const float g = -sinf(3.14159265358979323846f * xx);
    const float factor = fast_tanh(xx + 1.0f) * fast_tanh(xx - 1.0f) * fast_tanh(tt);
    out[list[i]] = fmaf(factor, u, g);
}
} // namespace

extern "C" void kernel_launch(void* const* d_in, const int* in_sizes, int n_in,
                              void* d_out, int out_size, void* d_ws, size_t ws_size,
                              hipStream_t stream) {
    const float* x       = (const float*)d_in[0];
    const float* lo_core = (const float*)d_in[1];
    const float* hi_core = (const float*)d_in[2];
    const float* lo_ext  = (const float*)d_in[3];
    const float* hi_ext  = (const float*)d_in[4];
    const float* W_in    = (const float*)d_in[5];
    const float* b_in    = (const float*)d_in[6];
    const float* W_h1    = (const float*)d_in[7];
    const float* b_h1    = (const float*)d_in[8];
    const float* W_h2    = (const float*)d_in[9];
    const float* b_h2    = (const float*)d_in[10];
    const float* W_out   = (const float*)d_in[11];
    const float* b_out   = (const float*)d_in[12];
    float* out = (float*)d_out;

    int* ws        = (int*)d_ws;
    int* off       = ws + WS_OFF;
    int* nch       = ws + WS_NCH;
    int* blockhist = ws + WS_BH;      // becomes per-(block,bucket) base after k_scan
    int* list      = ws + WS_LIST;
    float2* xsorted = (float2*)(ws + WS_XS);
    float2* part    = (float2*)(ws + WS_PART);
    int2*   desc    = (int2*)(ws + WS_DESC);

    hipLaunchKernelGGL(k_hist,    dim3(NBH),      dim3(BLK), 0, stream, x, blockhist);
    hipLaunchKernelGGL(k_scan,    dim3(1),        dim3(NBK), 0, stream, blockhist, off, nch, desc);
    hipLaunchKernelGGL(k_scatter, dim3(NBH),      dim3(BLK), 0, stream, x, blockhist, list, xsorted);
    hipLaunchKernelGGL(k_main,    dim3(NMB),      dim3(256), 0, stream,
        xsorted, lo_core, hi_core, lo_ext, hi_ext, W_in, b_in, W_h1, b_h1,
        W_h2, b_h2, W_out, b_out, nch, desc, part);
    hipLaunchKernelGGL(k_combine, dim3(NP / BLK), dim3(BLK), 0, stream, part, xsorted, list, out);
}